// Round 6
// baseline (266.413 us; speedup 1.0000x reference)
//
#include <hip/hip_runtime.h>
#include <hip/hip_bf16.h>
#include <stdint.h>

typedef __bf16 bf16x8 __attribute__((ext_vector_type(8)));
typedef float f32x4 __attribute__((ext_vector_type(4)));

#define RATIO   128
#define HEADDIM 512
#define RD      64
#define NCW     64
#define BATCH   2
#define SEQ     8192
#define DIM     4096

#define SBAR() __builtin_amdgcn_sched_barrier(0)
#define BARR() __builtin_amdgcn_s_barrier()

__device__ __forceinline__ void gload16(const void* g, void* l) {
  __builtin_amdgcn_global_load_lds(
      (__attribute__((address_space(1))) const void*)g,
      (__attribute__((address_space(3))) void*)l, 16, 0, 0);
}

__device__ __forceinline__ __bf16 cvt_bf16(float f) {
  __hip_bfloat16 h = __float2bfloat16(f);
  return *reinterpret_cast<__bf16*>(&h);
}

// ---------------- prep: build W' swizzled bf16 tiles ----------------
// W' col-in-block C (0..255): channel = j*128 + (C>>4)*8 + (C&7), tensor = (C>>3)&1
// (16-col fragment = 8 kv channels + the same 8 sc channels).
// Tile layout: [j 4][k0t 64][row 256][slot 8] chunks of 8 bf16 along k,
// chunk(row,slot) holds k = k0t*64 + (slot^(row&7))*8 .. +8  (XOR pre-swizzle).
__global__ __launch_bounds__(256) void prep_weights(
    const float* __restrict__ w0, const float* __restrict__ w1,
    __hip_bfloat16* __restrict__ wTs) {
  __shared__ float tile[2][64][128];
  const int k0t = blockIdx.x;   // 0..63
  const int j   = blockIdx.y;   // 0..3
  const int t   = threadIdx.x;
  const int kk  = t >> 5;       // 0..7
  const int c4  = (t & 31) * 4;
  #pragma unroll
  for (int tensor = 0; tensor < 2; ++tensor) {
    const float* in = tensor ? w1 : w0;
    #pragma unroll
    for (int p = 0; p < 8; ++p) {
      const int k = p * 8 + kk;
      const f32x4 v = *reinterpret_cast<const f32x4*>(
          in + (size_t)(k0t * 64 + k) * HEADDIM + j * 128 + c4);
      tile[tensor][k][c4 + 0] = v[0]; tile[tensor][k][c4 + 1] = v[1];
      tile[tensor][k][c4 + 2] = v[2]; tile[tensor][k][c4 + 3] = v[3];
    }
  }
  __syncthreads();
  const int row    = t;                          // 0..255
  const int chloc  = (row >> 4) * 8 + (row & 7); // 0..127
  const int tensor = (row >> 3) & 1;
  __hip_bfloat16* ob = wTs + (((size_t)j * 64 + k0t) * 2048 + (size_t)row * 8) * 8;
  #pragma unroll
  for (int slot = 0; slot < 8; ++slot) {
    const int k8 = (slot ^ (row & 7)) * 8;
    bf16x8 c;
    #pragma unroll
    for (int jj = 0; jj < 8; ++jj) c[jj] = cvt_bf16(tile[tensor][k8 + jj][chloc]);
    *reinterpret_cast<bf16x8*>(ob + slot * 8) = c;
  }
}

// ---------------- fused 256x256 GEMM + softmax-pool, 8-phase raw-barrier pipeline ----------------
__global__ __launch_bounds__(512, 2) void gemm_pool_kernel(
    const float* __restrict__ x,
    const __hip_bfloat16* __restrict__ wTs,
    const float* __restrict__ ape,       // [128][512] f32
    float* __restrict__ comp) {          // [2][64][512] f32
  __shared__ char smem[131072];          // 2 x (A 32KB + B 32KB)

  const int u      = blockIdx.x;                   // 256 blocks
  const int rowblk = ((u >> 3) & 7) * 8 + (u & 7); // u%8 == XCD; 4 colblks of a rowblk share it
  const int colblk = u >> 6;
  const int tid  = threadIdx.x;
  const int lane = tid & 63;
  const int wid  = tid >> 6;             // 8 waves: 2(M) x 4(N)
  const int wm   = wid >> 2, wn = wid & 3;

  const float* xw = x + (size_t)rowblk * 256 * DIM;
  const __hip_bfloat16* wsrc = wTs + (size_t)colblk * 64 * 2048 * 8;

  // A staging: 2 threads per row, each covers 32 f32 (8 f32x4) per K-tile
  const int arow  = tid >> 1;
  const int ahalf = tid & 1;
  const float* aBase = xw + (size_t)arow * DIM + ahalf * 32;

  f32x4 acc[8][4];
  #pragma unroll
  for (int i = 0; i < 8; ++i)
    #pragma unroll
    for (int j = 0; j < 4; ++j) acc[i][j] = {0.f, 0.f, 0.f, 0.f};

  auto issueA = [&](int k0t, f32x4* pv) {
    const f32x4* s = reinterpret_cast<const f32x4*>(aBase + k0t * 64);
    #pragma unroll
    for (int q = 0; q < 8; ++q) pv[q] = s[q];
  };
  auto issueB = [&](int k0t, char* bufB) {
    #pragma unroll
    for (int i = 0; i < 4; ++i) {
      const int ch = wid * 256 + i * 64;       // wave-uniform chunk base
      gload16(wsrc + ((size_t)k0t * 2048 + ch + lane) * 8, bufB + ch * 16);
    }
  };
  auto writeA = [&](char* bufA, const f32x4* pv) {
    char* ab = bufA + arow * 128;
    #pragma unroll
    for (int q = 0; q < 4; ++q) {
      bf16x8 c;
      #pragma unroll
      for (int jj = 0; jj < 4; ++jj) {
        c[jj]     = cvt_bf16(pv[2 * q][jj]);
        c[4 + jj] = cvt_bf16(pv[2 * q + 1][jj]);
      }
      *reinterpret_cast<bf16x8*>(ab + (((ahalf * 4 + q) ^ (arow & 7)) << 4)) = c;
    }
  };
  auto ldA = [&](const char* bufA, int half, int s, bf16x8* af) {
    const int c16 = s * 4 + (lane >> 4);
    #pragma unroll
    for (int mt = 0; mt < 4; ++mt) {
      const int r = wm * 128 + (half * 4 + mt) * 16 + (lane & 15);
      af[mt] = *reinterpret_cast<const bf16x8*>(bufA + r * 128 + ((c16 ^ (r & 7)) << 4));
    }
  };
  auto ldB = [&](const char* bufB, int s, bf16x8* bf) {
    const int c16 = s * 4 + (lane >> 4);
    #pragma unroll
    for (int nt = 0; nt < 4; ++nt) {
      const int cc = wn * 64 + nt * 16 + (lane & 15);
      bf[nt] = *reinterpret_cast<const bf16x8*>(bufB + cc * 128 + ((c16 ^ (cc & 7)) << 4));
    }
  };
  auto mfma16 = [&](const bf16x8* af, const bf16x8* bf, int half) {
    __builtin_amdgcn_s_setprio(1);
    #pragma unroll
    for (int nt = 0; nt < 4; ++nt)
      #pragma unroll
      for (int mt = 0; mt < 4; ++mt)
        acc[half * 4 + mt][nt] =
            __builtin_amdgcn_mfma_f32_16x16x32_bf16(af[mt], bf[nt], acc[half * 4 + mt][nt], 0, 0, 0);
    __builtin_amdgcn_s_setprio(0);
  };

  // prologue: stage K-tile 0 into buffer 0 (full drain once, via __syncthreads)
  {
    f32x4 pv0[8];
    issueA(0, pv0);
    issueB(0, smem + 32768);
    writeA(smem, pv0);
  }
  __syncthreads();

  int cur = 0;
  for (int t = 0; t < 64; ++t) {
    const char* A  = smem + (cur ? 65536 : 0);
    const char* B  = A + 32768;
    char* An = smem + (cur ? 0 : 65536);
    char* Bn = An + 32768;
    const bool pf = (t < 63);
    f32x4 pv[8];
    bf16x8 aflo[4], afhi[4], bfv[4];

    // ---- P0: reads(s0,lo)+B-frags | issue A(t+1)->regs | 16 MFMA
    ldA(A, 0, 0, aflo); ldB(B, 0, bfv);
    if (pf) issueA(t + 1, pv);
    SBAR(); BARR(); SBAR();
    mfma16(aflo, bfv, 0);
    SBAR(); BARR(); SBAR();

    // ---- P1: reads(s0,hi) | issue B(t+1)->LDS[next] | 16 MFMA
    ldA(A, 1, 0, afhi);
    if (pf) issueB(t + 1, Bn);
    SBAR(); BARR(); SBAR();
    mfma16(afhi, bfv, 1);
    SBAR(); BARR(); SBAR();

    // ---- P2: reads(s1,lo)+B-frags | cvt+ds_write A(t+1)->LDS[next] | 16 MFMA
    ldA(A, 0, 1, aflo); ldB(B, 1, bfv);
    if (pf) writeA(An, pv);            // compiler's precise vmcnt on pv use
    SBAR(); BARR(); SBAR();
    mfma16(aflo, bfv, 0);
    SBAR(); BARR(); SBAR();

    // ---- P3: reads(s1,hi) | 16 MFMA | publish next buffers
    ldA(A, 1, 1, afhi);
    SBAR(); BARR(); SBAR();
    mfma16(afhi, bfv, 1);
    if (pf) asm volatile("s_waitcnt vmcnt(0) lgkmcnt(0)" ::: "memory"); // B tail + A ds_write drain
    SBAR(); BARR(); SBAR();
    cur ^= 1;
  }

  // ---- epilogue: in-register softmax-pool; kv<->sc pairing via shfl_xor(8) ----
  const int win = rowblk * 2 + wm;       // global window id (= b*64 + nc)
  #pragma unroll
  for (int nt = 0; nt < 4; ++nt) {
    const int f  = wn * 4 + nt;
    const int ch = colblk * 128 + f * 8 + (lane & 7);
    if (lane & 8) {                      // hi lanes hold sc: add ape first
      #pragma unroll
      for (int mt = 0; mt < 8; ++mt)
        #pragma unroll
        for (int r = 0; r < 4; ++r) {
          const int rw = mt * 16 + ((lane >> 4) & 3) * 4 + r;
          acc[mt][nt][r] += ape[(size_t)rw * HEADDIM + ch];
        }
    }
    float m = -3.0e38f;
    #pragma unroll
    for (int mt = 0; mt < 8; ++mt)
      #pragma unroll
      for (int r = 0; r < 4; ++r) m = fmaxf(m, acc[mt][nt][r]);
    m = fmaxf(m, __shfl_xor(m, 16));
    m = fmaxf(m, __shfl_xor(m, 32));
    float den = 0.f, num = 0.f;
    #pragma unroll
    for (int mt = 0; mt < 8; ++mt)
      #pragma unroll
      for (int r = 0; r < 4; ++r) {
        const float other = __shfl_xor(acc[mt][nt][r], 8);  // hi lane gets kv
        const float e = __expf(acc[mt][nt][r] - m);
        den += e;
        num += e * other;
      }
    den += __shfl_xor(den, 16); den += __shfl_xor(den, 32);
    num += __shfl_xor(num, 16); num += __shfl_xor(num, 32);
    if ((lane & 8) && (lane < 16))
      comp[(size_t)win * HEADDIM + ch] = num / den;
  }
}

// ---------------- RMSNorm + RoPE + scatter (all f32) ----------------
__global__ __launch_bounds__(64) void finalize_kernel(
    const float* __restrict__ comp,
    const float* __restrict__ nw,
    const float* __restrict__ cosg,
    const float* __restrict__ sing,
    const int* __restrict__ bo,
    float* __restrict__ out) {
  const int win = blockIdx.x;          // 0..127
  const int b = win >> 6, nc = win & 63;
  const int t = threadIdx.x;
  const float* cw = comp + (size_t)win * HEADDIM;

  float v[8];
  float ss = 0.f;
  #pragma unroll
  for (int j = 0; j < 8; ++j) { v[j] = cw[t * 8 + j]; ss += v[j] * v[j]; }
  #pragma unroll
  for (int o = 32; o; o >>= 1) ss += __shfl_xor(ss, o);
  const float scale = rsqrtf(ss / 512.0f + 1e-6f);

  float w[8];
  #pragma unroll
  for (int j = 0; j < 8; ++j) w[j] = v[j] * scale * nw[t * 8 + j];

  const int phys = bo[b];
  float* op = out + ((size_t)phys * NCW + nc) * HEADDIM + t * 8;
  if (t * 8 < HEADDIM - RD) {
    #pragma unroll
    for (int j = 0; j < 8; ++j) op[j] = w[j];
  } else {
    const int pos = nc * RATIO;
    #pragma unroll
    for (int j = 0; j < 8; j += 2) {
      const int i = (t * 8 + j - (HEADDIM - RD)) >> 1;
      const float co = cosg[(size_t)pos * 32 + i];
      const float si = sing[(size_t)pos * 32 + i];
      op[j]     = w[j] * co - w[j + 1] * si;
      op[j + 1] = w[j] * si + w[j + 1] * co;
    }
  }
}

extern "C" void kernel_launch(void* const* d_in, const int* in_sizes, int n_in,
                              void* d_out, int out_size, void* d_ws, size_t ws_size,
                              hipStream_t stream) {
  const float* x     = (const float*)d_in[0];
  const float* wkv   = (const float*)d_in[1];
  const float* wgate = (const float*)d_in[2];
  const float* ape   = (const float*)d_in[3];
  const float* nw    = (const float*)d_in[4];
  const float* cosg  = (const float*)d_in[5];
  const float* sing  = (const float*)d_in[6];
  const int*   bo    = (const int*)d_in[7];
  float* out = (float*)d_out;

  __hip_bfloat16* wTs = (__hip_bfloat16*)d_ws;                        // 8 MB swizzled W'
  float* comp = (float*)((char*)d_ws + (size_t)8 * 1024 * 1024);      // 256 KB

  (void)hipMemsetAsync(d_out, 0, (size_t)out_size * sizeof(float), stream);
  prep_weights<<<dim3(64, 4), 256, 0, stream>>>(wkv, wgate, wTs);
  gemm_pool_kernel<<<dim3(256), 512, 0, stream>>>(x, wTs, ape, comp);
  finalize_kernel<<<dim3(128), 64, 0, stream>>>(comp, nw, cosg, sing, bo, out);
}

// Round 7
// 256.590 us; speedup vs baseline: 1.0383x; 1.0383x over previous
//
#include <hip/hip_runtime.h>
#include <hip/hip_bf16.h>
#include <stdint.h>

typedef __bf16 bf16x8 __attribute__((ext_vector_type(8)));
typedef float f32x4 __attribute__((ext_vector_type(4)));

#define RATIO   128
#define HEADDIM 512
#define RD      64
#define NCW     64
#define BATCH   2
#define SEQ     8192
#define DIM     4096

#define SBAR() __builtin_amdgcn_sched_barrier(0)
#define BARR() __builtin_amdgcn_s_barrier()

__device__ __forceinline__ void gload16(const void* g, void* l) {
  __builtin_amdgcn_global_load_lds(
      (__attribute__((address_space(1))) const void*)g,
      (__attribute__((address_space(3))) void*)l, 16, 0, 0);
}

__device__ __forceinline__ __bf16 cvt_bf16(float f) {
  __hip_bfloat16 h = __float2bfloat16(f);
  return *reinterpret_cast<__bf16*>(&h);
}

// ---------------- prep: build W' swizzled bf16 tiles ----------------
// W' col-in-block C (0..255): channel = j*128 + (C>>4)*8 + (C&7), tensor = (C>>3)&1
// Tile layout: [j 4][k0t 64][row 256][slot 8] chunks of 8 bf16 along k,
// chunk(row,slot) holds k = k0t*64 + (slot^(row&7))*8 .. +8  (XOR pre-swizzle).
__global__ __launch_bounds__(256) void prep_weights(
    const float* __restrict__ w0, const float* __restrict__ w1,
    __hip_bfloat16* __restrict__ wTs) {
  __shared__ float tile[2][64][128];
  const int k0t = blockIdx.x;   // 0..63
  const int j   = blockIdx.y;   // 0..3
  const int t   = threadIdx.x;
  const int kk  = t >> 5;       // 0..7
  const int c4  = (t & 31) * 4;
  #pragma unroll
  for (int tensor = 0; tensor < 2; ++tensor) {
    const float* in = tensor ? w1 : w0;
    #pragma unroll
    for (int p = 0; p < 8; ++p) {
      const int k = p * 8 + kk;
      const f32x4 v = *reinterpret_cast<const f32x4*>(
          in + (size_t)(k0t * 64 + k) * HEADDIM + j * 128 + c4);
      tile[tensor][k][c4 + 0] = v[0]; tile[tensor][k][c4 + 1] = v[1];
      tile[tensor][k][c4 + 2] = v[2]; tile[tensor][k][c4 + 3] = v[3];
    }
  }
  __syncthreads();
  const int row    = t;                          // 0..255
  const int chloc  = (row >> 4) * 8 + (row & 7); // 0..127
  const int tensor = (row >> 3) & 1;
  __hip_bfloat16* ob = wTs + (((size_t)j * 64 + k0t) * 2048 + (size_t)row * 8) * 8;
  #pragma unroll
  for (int slot = 0; slot < 8; ++slot) {
    const int k8 = (slot ^ (row & 7)) * 8;
    bf16x8 c;
    #pragma unroll
    for (int jj = 0; jj < 8; ++jj) c[jj] = cvt_bf16(tile[tensor][k8 + jj][chloc]);
    *reinterpret_cast<bf16x8*>(ob + slot * 8) = c;
  }
}

// ------- fused 256x256 GEMM + softmax-pool, aged-wait 4-phase pipeline -------
__global__ __launch_bounds__(512, 1) void gemm_pool_kernel(
    const float* __restrict__ x,
    const __hip_bfloat16* __restrict__ wTs,
    const float* __restrict__ ape,       // [128][512] f32
    float* __restrict__ comp) {          // [2][64][512] f32
  __shared__ char smem[131072];          // 2 x (A 32KB + B 32KB)

  const int u      = blockIdx.x;                   // 256 blocks
  const int rowblk = ((u >> 3) & 7) * 8 + (u & 7); // u&7 == XCD; 4 colblks of a rowblk share it
  const int colblk = u >> 6;
  const int tid  = threadIdx.x;
  const int lane = tid & 63;
  const int wid  = tid >> 6;             // 8 waves: 2(M) x 4(N)
  const int wm   = wid >> 2, wn = wid & 3;

  const float* xw = x + (size_t)rowblk * 256 * DIM;
  const __hip_bfloat16* wsrc = wTs + (size_t)colblk * 64 * 2048 * 8;

  // A staging: 2 threads per row, each covers 32 f32 per K-tile
  const int arow  = tid >> 1;
  const int ahalf = tid & 1;
  const float* aBase = xw + (size_t)arow * DIM + ahalf * 32;

  f32x4 acc[8][4];
  #pragma unroll
  for (int i = 0; i < 8; ++i)
    #pragma unroll
    for (int j = 0; j < 4; ++j) acc[i][j] = {0.f, 0.f, 0.f, 0.f};

  auto issueA = [&](int k0t, f32x4* pv) {
    const f32x4* s = reinterpret_cast<const f32x4*>(aBase + k0t * 64);
    #pragma unroll
    for (int q = 0; q < 8; ++q) pv[q] = s[q];
  };
  auto issueBunit = [&](int k0t, int ub, char* bufB) {  // ub: cols [ub*128, +128)
    #pragma unroll
    for (int i = 0; i < 2; ++i) {
      const int ch = ub * 1024 + wid * 128 + i * 64;   // wave-uniform chunk base
      gload16(wsrc + ((size_t)k0t * 2048 + ch + lane) * 8, bufB + ch * 16);
    }
  };
  auto writeAhalf = [&](char* bufA, const f32x4* pv, int h) {
    char* ab = bufA + arow * 128;
    #pragma unroll
    for (int q = 2 * h; q < 2 * h + 2; ++q) {
      bf16x8 c;
      #pragma unroll
      for (int jj = 0; jj < 4; ++jj) {
        c[jj]     = cvt_bf16(pv[2 * q][jj]);
        c[4 + jj] = cvt_bf16(pv[2 * q + 1][jj]);
      }
      *reinterpret_cast<bf16x8*>(ab + (((ahalf * 4 + q) ^ (arow & 7)) << 4)) = c;
    }
  };
  auto ldAq = [&](const char* bufA, int q, bf16x8* afr) {  // quadrant q: mt {2q,2q+1}
    #pragma unroll
    for (int j = 0; j < 2; ++j)
      #pragma unroll
      for (int s = 0; s < 2; ++s) {
        const int r = wm * 128 + (q * 2 + j) * 16 + (lane & 15);
        const int c16 = s * 4 + (lane >> 4);
        afr[j * 2 + s] = *reinterpret_cast<const bf16x8*>(
            bufA + r * 128 + ((c16 ^ (r & 7)) << 4));
      }
  };
  auto ldBall = [&](const char* bufB, bf16x8* bfr) {       // all 8 B-frags of the K-tile
    #pragma unroll
    for (int nt = 0; nt < 4; ++nt)
      #pragma unroll
      for (int s = 0; s < 2; ++s) {
        const int cc = wn * 64 + nt * 16 + (lane & 15);
        const int c16 = s * 4 + (lane >> 4);
        bfr[nt * 2 + s] = *reinterpret_cast<const bf16x8*>(
            bufB + cc * 128 + ((c16 ^ (cc & 7)) << 4));
      }
  };
  auto mfmaq = [&](const bf16x8* afr, const bf16x8* bfr, int q) {  // 16 MFMA
    __builtin_amdgcn_s_setprio(1);
    #pragma unroll
    for (int s = 0; s < 2; ++s)
      #pragma unroll
      for (int nt = 0; nt < 4; ++nt)
        #pragma unroll
        for (int j = 0; j < 2; ++j)
          acc[q * 2 + j][nt] = __builtin_amdgcn_mfma_f32_16x16x32_bf16(
              afr[j * 2 + s], bfr[nt * 2 + s], acc[q * 2 + j][nt], 0, 0, 0);
    __builtin_amdgcn_s_setprio(0);
  };

  // prologue: fully stage K-tile 0 into buffer 0
  {
    f32x4 pv[8];
    issueA(0, pv);
    issueBunit(0, 0, smem + 32768);
    issueBunit(0, 1, smem + 32768);
    writeAhalf(smem, pv, 0);   // reg-dep waits the A loads
    writeAhalf(smem, pv, 1);
  }
  __syncthreads();             // one-time full drain

  for (int t = 0; t < 64; ++t) {
    const int cur = t & 1;
    const char* A = smem + cur * 65536;
    const char* B = A + 32768;
    char* An = smem + (cur ^ 1) * 65536;
    char* Bn = An + 32768;
    const bool pf = (t < 63);
    f32x4 nv[8];
    bf16x8 bfr[8], afr[4];

    // ---- phase 0: B-frags + A-frags(q0) | issue A(t+1)->regs | 16 MFMA
    ldBall(B, bfr);
    ldAq(A, 0, afr);
    if (pf) issueA(t + 1, nv);
    mfmaq(afr, bfr, 0);
    BARR(); SBAR();

    // ---- phase 1: A-frags(q1) | issue B unit0 (t+1) | 16 MFMA
    ldAq(A, 1, afr);
    if (pf) issueBunit(t + 1, 0, Bn);
    mfmaq(afr, bfr, 1);
    BARR(); SBAR();

    // ---- phase 2: A-frags(q2) | issue B unit1 (t+1) | ds_write A half0 | 16 MFMA
    ldAq(A, 2, afr);
    if (pf) issueBunit(t + 1, 1, Bn);
    if (pf) writeAhalf(An, nv, 0);      // A-regs issued 2 phases ago
    mfmaq(afr, bfr, 2);
    BARR(); SBAR();

    // ---- phase 3: A-frags(q3) | ds_write A half1 | 16 MFMA | aged waits
    ldAq(A, 3, afr);
    if (pf) writeAhalf(An, nv, 1);
    mfmaq(afr, bfr, 3);
    if (pf) asm volatile("s_waitcnt vmcnt(0) lgkmcnt(0)" ::: "memory");
    BARR(); SBAR();
  }

  // ---- epilogue: in-register softmax-pool; kv<->sc pairing via shfl_xor(8) ----
  const int win = rowblk * 2 + wm;       // global window id (= b*64 + nc)
  #pragma unroll
  for (int nt = 0; nt < 4; ++nt) {
    const int f  = wn * 4 + nt;
    const int ch = colblk * 128 + f * 8 + (lane & 7);
    if (lane & 8) {                      // hi lanes hold sc: add ape first
      #pragma unroll
      for (int mt = 0; mt < 8; ++mt)
        #pragma unroll
        for (int r = 0; r < 4; ++r) {
          const int rw = mt * 16 + ((lane >> 4) & 3) * 4 + r;
          acc[mt][nt][r] += ape[(size_t)rw * HEADDIM + ch];
        }
    }
    float m = -3.0e38f;
    #pragma unroll
    for (int mt = 0; mt < 8; ++mt)
      #pragma unroll
      for (int r = 0; r < 4; ++r) m = fmaxf(m, acc[mt][nt][r]);
    m = fmaxf(m, __shfl_xor(m, 16));
    m = fmaxf(m, __shfl_xor(m, 32));
    float den = 0.f, num = 0.f;
    #pragma unroll
    for (int mt = 0; mt < 8; ++mt)
      #pragma unroll
      for (int r = 0; r < 4; ++r) {
        const float other = __shfl_xor(acc[mt][nt][r], 8);  // hi lane gets kv
        const float e = __expf(acc[mt][nt][r] - m);
        den += e;
        num += e * other;
      }
    den += __shfl_xor(den, 16); den += __shfl_xor(den, 32);
    num += __shfl_xor(num, 16); num += __shfl_xor(num, 32);
    if ((lane & 8) && (lane < 16))
      comp[(size_t)win * HEADDIM + ch] = num / den;
  }
}

// ---------------- RMSNorm + RoPE + scatter (all f32) ----------------
__global__ __launch_bounds__(64) void finalize_kernel(
    const float* __restrict__ comp,
    const float* __restrict__ nw,
    const float* __restrict__ cosg,
    const float* __restrict__ sing,
    const int* __restrict__ bo,
    float* __restrict__ out) {
  const int win = blockIdx.x;          // 0..127
  const int b = win >> 6, nc = win & 63;
  const int t = threadIdx.x;
  const float* cw = comp + (size_t)win * HEADDIM;

  float v[8];
  float ss = 0.f;
  #pragma unroll
  for (int j = 0; j < 8; ++j) { v[j] = cw[t * 8 + j]; ss += v[j] * v[j]; }
  #pragma unroll
  for (int o = 32; o; o >>= 1) ss += __shfl_xor(ss, o);
  const float scale = rsqrtf(ss / 512.0f + 1e-6f);

  float w[8];
  #pragma unroll
  for (int j = 0; j < 8; ++j) w[j] = v[j] * scale * nw[t * 8 + j];

  const int phys = bo[b];
  float* op = out + ((size_t)phys * NCW + nc) * HEADDIM + t * 8;
  if (t * 8 < HEADDIM - RD) {
    #pragma unroll
    for (int j = 0; j < 8; ++j) op[j] = w[j];
  } else {
    const int pos = nc * RATIO;
    #pragma unroll
    for (int j = 0; j < 8; j += 2) {
      const int i = (t * 8 + j - (HEADDIM - RD)) >> 1;
      const float co = cosg[(size_t)pos * 32 + i];
      const float si = sing[(size_t)pos * 32 + i];
      op[j]     = w[j] * co - w[j + 1] * si;
      op[j + 1] = w[j] * si + w[j + 1] * co;
    }
  }
}

extern "C" void kernel_launch(void* const* d_in, const int* in_sizes, int n_in,
                              void* d_out, int out_size, void* d_ws, size_t ws_size,
                              hipStream_t stream) {
  const float* x     = (const float*)d_in[0];
  const float* wkv   = (const float*)d_in[1];
  const float* wgate = (const float*)d_in[2];
  const float* ape   = (const float*)d_in[3];
  const float* nw    = (const float*)d_in[4];
  const float* cosg  = (const float*)d_in[5];
  const float* sing  = (const float*)d_in[6];
  const int*   bo    = (const int*)d_in[7];
  float* out = (float*)d_out;

  __hip_bfloat16* wTs = (__hip_bfloat16*)d_ws;                        // 8 MB swizzled W'
  float* comp = (float*)((char*)d_ws + (size_t)8 * 1024 * 1024);      // 256 KB

  (void)hipMemsetAsync(d_out, 0, (size_t)out_size * sizeof(float), stream);
  prep_weights<<<dim3(64, 4), 256, 0, stream>>>(wkv, wgate, wTs);
  gemm_pool_kernel<<<dim3(256), 512, 0, stream>>>(x, wTs, ape, comp);
  finalize_kernel<<<dim3(128), 64, 0, stream>>>(comp, nw, cosg, sing, bo, out);
}

// Round 9
// 209.638 us; speedup vs baseline: 1.2708x; 1.2240x over previous
//
#include <hip/hip_runtime.h>
#include <hip/hip_bf16.h>
#include <stdint.h>

typedef __bf16 bf16x8 __attribute__((ext_vector_type(8)));
typedef float f32x4 __attribute__((ext_vector_type(4)));

#define RATIO   128
#define HEADDIM 512
#define RD      64
#define NCW     64
#define BATCH   2
#define SEQ     8192
#define DIM     4096

#define SBAR() __builtin_amdgcn_sched_barrier(0)
#define BARR() __builtin_amdgcn_s_barrier()

__device__ __forceinline__ void gload16(const void* g, void* l) {
  __builtin_amdgcn_global_load_lds(
      (__attribute__((address_space(1))) const void*)g,
      (__attribute__((address_space(3))) void*)l, 16, 0, 0);
}

__device__ __forceinline__ __bf16 cvt_bf16(float f) {
  __hip_bfloat16 h = __float2bfloat16(f);
  return *reinterpret_cast<__bf16*>(&h);
}

// ---------------- prep: f32 weights -> swizzled bf16 tiles (R3-verified) ----------------
// wTs layout: [wsel 2][hb 4][k0t 64] tiles; tile = [row 128][slot 8] chunks of 8 bf16.
// chunk (row, slot) holds w[k0t*64 + (slot^(row&7))*8 .. +8][hb*128+row].
__global__ __launch_bounds__(256) void prep_weights(
    const float* __restrict__ w0, const float* __restrict__ w1,
    __hip_bfloat16* __restrict__ wTs) {
  __shared__ float tile[64][132];
  const int wsel = blockIdx.z, hb = blockIdx.y, k0t = blockIdx.x;
  const float* in = wsel ? w1 : w0;
  const int t = threadIdx.x;
  const int h4 = (t & 31) * 4;
  #pragma unroll
  for (int p = 0; p < 8; ++p) {
    const int k = (t >> 5) + p * 8;
    const f32x4 v = *reinterpret_cast<const f32x4*>(
        in + (size_t)(k0t * 64 + k) * HEADDIM + hb * 128 + h4);
    tile[k][h4 + 0] = v[0]; tile[k][h4 + 1] = v[1];
    tile[k][h4 + 2] = v[2]; tile[k][h4 + 3] = v[3];
  }
  __syncthreads();
  const int row = t >> 1;
  __hip_bfloat16* outbase =
      wTs + (((size_t)(wsel * 4 + hb) * 64 + k0t) * 1024 + (size_t)row * 8) * 8;
  #pragma unroll
  for (int q = 0; q < 4; ++q) {
    const int slot = (t & 1) * 4 + q;
    const int kk = (slot ^ (row & 7)) * 8;
    bf16x8 c;
    #pragma unroll
    for (int j = 0; j < 8; ++j) c[j] = cvt_bf16(tile[kk + j][row]);
    *reinterpret_cast<bf16x8*>(outbase + slot * 8) = c;
  }
}

// swizzled fragment read: 8 bf16 at (row, 16B-chunk c16)
__device__ __forceinline__ bf16x8 ldfrag(const char* s, int row, int c16) {
  return *reinterpret_cast<const bf16x8*>(s + row * 128 + ((c16 ^ (row & 7)) << 4));
}

// -------- fused GEMM (kv + gate) + softmax-pool; R3 geometry + aged prefetch --------
__global__ __launch_bounds__(256, 2) void gemm_pool_kernel(
    const float* __restrict__ x,
    const __hip_bfloat16* __restrict__ wTs,
    const float* __restrict__ ape,       // [128][512] f32
    float* __restrict__ comp) {          // [2][64][512] f32
  __shared__ char smem[81920];           // sA 16K | sKV0 | sKV1 | sSC0 | sSC1 (16K each)
  char* sA = smem;

  const int u    = blockIdx.x;
  const int xcd  = u & 7;
  const int slot = u >> 3;
  const int win  = xcd + 8 * (slot >> 2);  // 4 hb-blocks of a window share an XCD
  const int hb   = slot & 3;
  const int b    = win >> 6;
  const int nc   = win & 63;

  const int tid  = threadIdx.x;
  const int lane = tid & 63;
  const int wid  = tid >> 6;
  const int wm   = wid >> 1, wn = wid & 1;

  const float* xw = x + ((size_t)b * SEQ + (size_t)nc * RATIO) * DIM;
  const __hip_bfloat16* kvTiles = wTs + ((size_t)(0 * 4 + hb) * 64) * 8192;
  const __hip_bfloat16* scTiles = wTs + ((size_t)(1 * 4 + hb) * 64) * 8192;

  f32x4 acc_kv[4][4], acc_sc[4][4];
  #pragma unroll
  for (int i = 0; i < 4; ++i)
    #pragma unroll
    for (int j = 0; j < 4; ++j) {
      acc_kv[i][j] = {0.f, 0.f, 0.f, 0.f};
      acc_sc[i][j] = {0.f, 0.f, 0.f, 0.f};
    }

  const int arow  = tid >> 1;         // 0..127
  const int ahalf = tid & 1;          // which 32-f32 half of the 64-k tile
  const float* aBase = xw + (size_t)arow * DIM + ahalf * 32;

  auto issueA = [&](int k0t, f32x4* pv) {
    const f32x4* s = reinterpret_cast<const f32x4*>(aBase + k0t * 64);
    #pragma unroll
    for (int q = 0; q < 8; ++q) pv[q] = s[q];
  };
  auto issueB = [&](int k0t, char* bKV, char* bSC) {
    #pragma unroll
    for (int i = 0; i < 4; ++i) {
      const int ch = wid * 256 + i * 64;     // wave-uniform chunk base
      gload16(kvTiles + ((size_t)k0t * 1024 + ch + lane) * 8, bKV + ch * 16);
      gload16(scTiles + ((size_t)k0t * 1024 + ch + lane) * 8, bSC + ch * 16);
    }
  };
  auto writeA = [&](const f32x4* pv) {
    char* ab = sA + arow * 128;
    #pragma unroll
    for (int q = 0; q < 4; ++q) {
      bf16x8 c;
      #pragma unroll
      for (int jj = 0; jj < 4; ++jj) {
        c[jj]     = cvt_bf16(pv[2 * q][jj]);
        c[4 + jj] = cvt_bf16(pv[2 * q + 1][jj]);
      }
      *reinterpret_cast<bf16x8*>(ab + (((ahalf * 4 + q) ^ (arow & 7)) << 4)) = c;
    }
  };
  auto compute = [&](const char* bKV, const char* bSC) {
    #pragma unroll
    for (int s = 0; s < 2; ++s) {
      const int c16 = s * 4 + (lane >> 4);
      bf16x8 af[4];
      #pragma unroll
      for (int mt = 0; mt < 4; ++mt)
        af[mt] = ldfrag(sA, wm * 64 + mt * 16 + (lane & 15), c16);
      #pragma unroll
      for (int nt = 0; nt < 4; ++nt) {
        const int brow = wn * 64 + nt * 16 + (lane & 15);
        const bf16x8 bkv = ldfrag(bKV, brow, c16);
        const bf16x8 bsc = ldfrag(bSC, brow, c16);
        #pragma unroll
        for (int mt = 0; mt < 4; ++mt) {
          acc_kv[mt][nt] = __builtin_amdgcn_mfma_f32_16x16x32_bf16(af[mt], bkv, acc_kv[mt][nt], 0, 0, 0);
          acc_sc[mt][nt] = __builtin_amdgcn_mfma_f32_16x16x32_bf16(af[mt], bsc, acc_sc[mt][nt], 0, 0, 0);
        }
      }
    }
  };

  // prologue: fully stage K-tile 0 (A -> sA, B -> buf 0)
  {
    f32x4 pv[8];
    issueA(0, pv);
    issueB(0, smem + 16384, smem + 49152);
    writeA(pv);                    // reg-dep waits the A loads
  }
  __syncthreads();                 // one-time full drain

  for (int t = 0; t < 64; ++t) {
    const int cur = t & 1;
    char* bKV  = smem + 16384 + cur * 16384;
    char* bSC  = smem + 49152 + cur * 16384;
    char* bKVn = smem + 16384 + (cur ^ 1) * 16384;
    char* bSCn = smem + 49152 + (cur ^ 1) * 16384;
    const bool pf = (t < 63);
    f32x4 nv[8];
    if (pf) {
      issueB(t + 1, bKVn, bSCn);    // L2-hot, aged by a full compute
      issueA(t + 1, nv);            // HBM, aged by a full compute
      SBAR();                       // pin issue before compute
    }
    compute(bKV, bSC);              // 64 MFMA/wave + 24 ds_read_b128
    BARR(); SBAR();                 // all waves done reading sA (no drain)
    if (pf) writeA(nv);             // cvt+ds_write A(t+1) into sA
    __syncthreads();                // publish; drains aged loads only
  }

  // ---- epilogue: softmax over the 128 window rows, pooled sum (R3-verified) ----
  float* redp = (float*)smem;           // red[3][2][128] aliases sA (dead now)
  auto RED = [&](int a, int b2, int c) -> float& { return redp[(a * 2 + b2) * 128 + c]; };
  const int cl = lane & 15;
  const int g4 = (lane >> 4) * 4;

  #pragma unroll
  for (int nt = 0; nt < 4; ++nt) {
    const int h = hb * 128 + wn * 64 + nt * 16 + cl;
    #pragma unroll
    for (int mt = 0; mt < 4; ++mt) {
      const int rbase = wm * 64 + mt * 16 + g4;
      #pragma unroll
      for (int r = 0; r < 4; ++r)
        acc_sc[mt][nt][r] += ape[(size_t)(rbase + r) * HEADDIM + h];
    }
  }

  float mx[4];
  #pragma unroll
  for (int nt = 0; nt < 4; ++nt) {
    float m = -3.0e38f;
    #pragma unroll
    for (int mt = 0; mt < 4; ++mt)
      #pragma unroll
      for (int r = 0; r < 4; ++r) m = fmaxf(m, acc_sc[mt][nt][r]);
    m = fmaxf(m, __shfl_xor(m, 16));
    m = fmaxf(m, __shfl_xor(m, 32));
    mx[nt] = m;
  }
  if (lane < 16) {
    #pragma unroll
    for (int nt = 0; nt < 4; ++nt)
      RED(0, wm, wn * 64 + nt * 16 + lane) = mx[nt];
  }
  __syncthreads();
  #pragma unroll
  for (int nt = 0; nt < 4; ++nt) {
    const int idx = wn * 64 + nt * 16 + cl;
    mx[nt] = fmaxf(RED(0, 0, idx), RED(0, 1, idx));
  }
  __syncthreads();

  float den[4], num[4];
  #pragma unroll
  for (int nt = 0; nt < 4; ++nt) {
    float d = 0.f, n = 0.f;
    #pragma unroll
    for (int mt = 0; mt < 4; ++mt)
      #pragma unroll
      for (int r = 0; r < 4; ++r) {
        const float e = __expf(acc_sc[mt][nt][r] - mx[nt]);
        d += e;
        n += e * acc_kv[mt][nt][r];
      }
    d += __shfl_xor(d, 16); d += __shfl_xor(d, 32);
    n += __shfl_xor(n, 16); n += __shfl_xor(n, 32);
    den[nt] = d; num[nt] = n;
  }
  if (lane < 16) {
    #pragma unroll
    for (int nt = 0; nt < 4; ++nt) {
      const int idx = wn * 64 + nt * 16 + lane;
      RED(1, wm, idx) = den[nt];
      RED(2, wm, idx) = num[nt];
    }
  }
  __syncthreads();
  if (wm == 0 && lane < 16) {
    #pragma unroll
    for (int nt = 0; nt < 4; ++nt) {
      const int idx = wn * 64 + nt * 16 + lane;
      const float dt = RED(1, 0, idx) + RED(1, 1, idx);
      const float nu = RED(2, 0, idx) + RED(2, 1, idx);
      comp[((size_t)b * NCW + nc) * HEADDIM + hb * 128 + idx] = nu / dt;
    }
  }
}

// ---------------- RMSNorm + RoPE + scatter (all f32) ----------------
__global__ __launch_bounds__(64) void finalize_kernel(
    const float* __restrict__ comp,
    const float* __restrict__ nw,
    const float* __restrict__ cosg,
    const float* __restrict__ sing,
    const int* __restrict__ bo,
    float* __restrict__ out) {
  const int win = blockIdx.x;          // 0..127
  const int b = win >> 6, nc = win & 63;
  const int t = threadIdx.x;
  const float* cw = comp + (size_t)win * HEADDIM;

  float v[8];
  float ss = 0.f;
  #pragma unroll
  for (int j = 0; j < 8; ++j) { v[j] = cw[t * 8 + j]; ss += v[j] * v[j]; }
  #pragma unroll
  for (int o = 32; o; o >>= 1) ss += __shfl_xor(ss, o);
  const float scale = rsqrtf(ss / 512.0f + 1e-6f);

  float w[8];
  #pragma unroll
  for (int j = 0; j < 8; ++j) w[j] = v[j] * scale * nw[t * 8 + j];

  const int phys = bo[b];
  float* op = out + ((size_t)phys * NCW + nc) * HEADDIM + t * 8;
  if (t * 8 < HEADDIM - RD) {
    #pragma unroll
    for (int j = 0; j < 8; ++j) op[j] = w[j];
  } else {
    const int pos = nc * RATIO;
    #pragma unroll
    for (int j = 0; j < 8; j += 2) {
      const int i = (t * 8 + j - (HEADDIM - RD)) >> 1;
      const float co = cosg[(size_t)pos * 32 + i];
      const float si = sing[(size_t)pos * 32 + i];
      op[j]     = w[j] * co - w[j + 1] * si;
      op[j + 1] = w[j] * si + w[j + 1] * co;
    }
  }
}

extern "C" void kernel_launch(void* const* d_in, const int* in_sizes, int n_in,
                              void* d_out, int out_size, void* d_ws, size_t ws_size,
                              hipStream_t stream) {
  const float* x     = (const float*)d_in[0];
  const float* wkv   = (const float*)d_in[1];
  const float* wgate = (const float*)d_in[2];
  const float* ape   = (const float*)d_in[3];
  const float* nw    = (const float*)d_in[4];
  const float* cosg  = (const float*)d_in[5];
  const float* sing  = (const float*)d_in[6];
  const int*   bo    = (const int*)d_in[7];
  float* out = (float*)d_out;

  __hip_bfloat16* wTs = (__hip_bfloat16*)d_ws;                        // 8 MB swizzled tiles
  float* comp = (float*)((char*)d_ws + (size_t)8 * 1024 * 1024);      // 256 KB

  (void)hipMemsetAsync(d_out, 0, (size_t)out_size * sizeof(float), stream);
  prep_weights<<<dim3(64, 4, 2), 256, 0, stream>>>(wkv, wgate, wTs);
  gemm_pool_kernel<<<dim3(512), 256, 0, stream>>>(x, wTs, ape, comp);
  finalize_kernel<<<dim3(128), 64, 0, stream>>>(comp, nw, cosg, sing, bo, out);
}